// Round 2
// baseline (507.955 us; speedup 1.0000x reference)
//
#include <hip/hip_runtime.h>

// InverseBarkScale: 30-iter SGD with momentum inverting a bark filterbank.
// fb (513x128) has <=2 nonzeros per freq row (triangular filters).
//
// R2 design: one wave per row (2048 single-wave blocks). Per-lane state in
// registers: spec[9], buf[9], taps {k1,w1,k2,w2}[9] for f=lane+64s, and the
// two bark targets m0,m1 (lane owns columns lane, lane+64). Forward is a
// per-freq SCATTER into LDS via ds_add_f32 (fixed 18 atomics/lane) instead of
// the R1 variable-trip per-column gather (up to ~40 serial conflicted LDS
// reads) -- that gather was ~37% bank-conflict cycles and 10k cyc/iter.
// Backward is 18 independent ds_read_b32, mostly same-address broadcasts.
// Double-buffered proj array avoids an extra barrier for re-zeroing.
//
// Stop-semantics: speculate 30 iters, record deterministic per-row loss
// partials, reduce -> losses[30] -> S; repair kernel re-runs with S iters
// only if S<30 (for this data S=30, so it exits immediately).

#define NSTFT 513
#define NBARK 128
#define BATCH 4
#define TIME  512
#define MAXIT 30
#define NROWS (BATCH*TIME)          // 2048 rows, 1 wave each

// d_ws layout (bytes), ~254 KB. All fields written before read each call.
#define WS_S_OFF   0                         // int: stop iteration S
#define WS_L_OFF   16                        // float[MAXIT]: losses
#define WS_FT_OFF  256                       // float4[NSTFT]: {k1,w1,k2,w2}
#define WS_BP_OFF  (256 + 16*NSTFT + 48)     // float[MAXIT][NROWS] partials
                                             // (8464+48=8512, 16B aligned)

__global__ __launch_bounds__(128) void setup_kernel(const float* __restrict__ fb,
                                                    char* __restrict__ ws) {
    int f = blockIdx.x * blockDim.x + threadIdx.x;
    if (f >= NSTFT) return;
    float4* ftab = (float4*)(ws + WS_FT_OFF);
    int k1 = 0, k2 = 0, c = 0;
    float w1 = 0.f, w2 = 0.f;
    for (int k = 0; k < NBARK; ++k) {
        float w = fb[f*NBARK + k];
        if (w > 0.f) {
            if (c == 0)      { k1 = k; w1 = w; }
            else if (c == 1) { k2 = k; w2 = w; }
            ++c;
        }
    }
    if (c < 2) { k2 = k1; w2 = 0.f; }        // 0/1-nnz rows: second tap is 0
    float4 e;
    e.x = __int_as_float(k1); e.y = w1;
    e.z = __int_as_float(k2); e.w = w2;
    ftab[f] = e;
}

__global__ __launch_bounds__(64) void
iter_kernel(const float* __restrict__ barkspec,
            const float* __restrict__ spec_init,
            float* __restrict__ out,
            char* __restrict__ ws, int mode)
{
    __shared__ float sproj[2][NBARK];        // double-buffered proj/diff

    const int lane = threadIdx.x;            // single wave per block

    int niter = MAXIT;
    if (mode) {
        int S = *(const volatile int*)(ws + WS_S_OFF);
        if (S >= MAXIT) return;              // expected path: no repair
        niter = S;
    }

    const int r     = blockIdx.x;            // row = (batch, t)
    const int batch = r >> 9;
    const int t     = r & (TIME - 1);

    // ---- registerize everything owned by this lane ----
    // bark columns (targets): lane and lane+64
    const int c0 = lane, c1 = lane + 64;
    const float* bs = barkspec + (size_t)batch*NBARK*TIME + t;
    const float m0 = bs[c0*TIME];
    const float m1 = bs[c1*TIME];

    // freq slices f = lane + 64*s, s=0..8 (f=512 only on lane 0)
    const float4* ftab = (const float4*)(ws + WS_FT_OFF);
    const float* sp = spec_init + ((size_t)batch*TIME + t)*NSTFT;
    int   k1[9], k2[9];
    float w1[9], w2[9], spec[9], buf[9];
#pragma unroll
    for (int s = 0; s < 9; ++s) {
        int f = lane + 64*s;
        if (f < NSTFT) {
            float4 e = ftab[f];              // coalesced, L2-resident
            k1[s] = __float_as_int(e.x); w1[s] = e.y;
            k2[s] = __float_as_int(e.z); w2[s] = e.w;
            spec[s] = sp[f];                 // coalesced
        } else {
            k1[s] = 0; k2[s] = 0; w1[s] = 0.f; w2[s] = 0.f; spec[s] = 0.f;
        }
        buf[s] = 0.f;
    }

    sproj[0][c0] = 0.f; sproj[0][c1] = 0.f;
    sproj[1][c0] = 0.f; sproj[1][c1] = 0.f;
    __syncthreads();

    float* bp = (float*)(ws + WS_BP_OFF);
    const float GC = -2.0f / (float)NROWS;   // -2 * inv_n

    for (int it = 0; it < niter; ++it) {
        const int cur = it & 1, nxt = cur ^ 1;

        // ---- forward scatter: proj[k] += spec[f]*fb[f,k] (18 ds_add_f32)
#pragma unroll
        for (int s = 0; s < 9; ++s) {
            int f = lane + 64*s;
            if (f < NSTFT) {
                atomicAdd(&sproj[cur][k1[s]], spec[s]*w1[s]);
                atomicAdd(&sproj[cur][k2[s]], spec[s]*w2[s]);
            }
        }
        __syncthreads();

        // ---- per-column: d = m - proj; write back; zero other buffer
        {
            float d0 = m0 - sproj[cur][c0];
            float d1 = m1 - sproj[cur][c1];
            sproj[cur][c0] = d0; sproj[cur][c1] = d1;
            sproj[nxt][c0] = 0.f; sproj[nxt][c1] = 0.f;
            if (!mode) {
                float lp = fmaf(d0, d0, d1*d1);
#pragma unroll
                for (int msk = 32; msk; msk >>= 1) lp += __shfl_xor(lp, msk);
                if (lane == 0) bp[it*NROWS + r] = lp;   // fire-and-forget
            }
        }
        __syncthreads();

        // ---- backward gather (18 independent ds_read_b32) + SGD update
#pragma unroll
        for (int s = 0; s < 9; ++s) {
            int f = lane + 64*s;
            if (f < NSTFT) {
                float g  = GC * fmaf(sproj[cur][k1[s]], w1[s],
                                     sproj[cur][k2[s]] * w2[s]);
                float b2 = fmaf(0.9f, buf[s], g);
                buf[s] = b2;
                float v = fmaf(-0.1f, b2, spec[s]);
                spec[s] = v < 0.f ? 0.f : v;
            }
        }
        __syncthreads();   // gather(it) done before transform(it+1) zeroes
    }

    // ---- store: out[batch, f, t] (scatter; L2 merges lines)
    float* og = out + ((size_t)batch*NSTFT)*TIME + t;
#pragma unroll
    for (int s = 0; s < 9; ++s) {
        int f = lane + 64*s;
        if (f < NSTFT) og[(size_t)f*TIME] = spec[s];
    }
}

// one block per iteration: reduce 2048 partials -> losses[it]
__global__ __launch_bounds__(256) void scan_reduce(char* __restrict__ ws) {
    __shared__ float wsum[4];
    const int it  = blockIdx.x;
    const int tid = threadIdx.x, wave = tid >> 6, lane = tid & 63;
    const float* bp = (const float*)(ws + WS_BP_OFF) + it*NROWS;
    float s = 0.f;
#pragma unroll
    for (int j = 0; j < NROWS/256; ++j) s += bp[tid + 256*j];
#pragma unroll
    for (int msk = 32; msk; msk >>= 1) s += __shfl_xor(s, msk);
    if (lane == 0) wsum[wave] = s;
    __syncthreads();
    if (tid == 0) {
        float tot = wsum[0] + wsum[1] + wsum[2] + wsum[3];
        ((float*)(ws + WS_L_OFF))[it] = tot * (1.0f/(float)NROWS);
    }
}

__global__ void scan_final(char* __restrict__ ws) {
    // reference stop logic: update applied on the stop iteration, frozen
    // after -> S = first stop index + 1, else MAXIT
    const float* losses = (const float*)(ws + WS_L_OFF);
    float prev = __builtin_inff();
    int S = MAXIT;
    for (int i = 0; i < MAXIT; ++i) {
        float l = losses[i];
        if (l < 1e-5f || fabsf(prev - l) < 1e-8f) { S = i + 1; break; }
        prev = l;
    }
    *(int*)(ws + WS_S_OFF) = S;
}

extern "C" void kernel_launch(void* const* d_in, const int* in_sizes, int n_in,
                              void* d_out, int out_size, void* d_ws, size_t ws_size,
                              hipStream_t stream)
{
    const float* barkspec  = (const float*)d_in[0];
    const float* fb        = (const float*)d_in[1];
    const float* spec_init = (const float*)d_in[2];
    float* out = (float*)d_out;
    char* ws = (char*)d_ws;

    setup_kernel<<<5, 128, 0, stream>>>(fb, ws);
    iter_kernel<<<NROWS, 64, 0, stream>>>(barkspec, spec_init, out, ws, 0);
    scan_reduce<<<MAXIT, 256, 0, stream>>>(ws);
    scan_final<<<1, 1, 0, stream>>>(ws);
    iter_kernel<<<NROWS, 64, 0, stream>>>(barkspec, spec_init, out, ws, 1);
}

// Round 3
// 150.282 us; speedup vs baseline: 3.3800x; 3.3800x over previous
//
#include <hip/hip_runtime.h>

// InverseBarkScale: 30-iter SGD with momentum inverting a bark filterbank.
// fb (513x128): each freq row has <=2 nonzeros in CONSECUTIVE columns (k,k+1);
// each column's support is a CONSECUTIVE freq run (triangular filters).
//
// R3: wave-per-row gather, no atomics, no barriers.
//  - forward: lane owns column pair (lane, 127-lane); widths are monotone in
//    k so pair sums are balanced (max ~11 quads). Support runs read as
//    ALIGNED float4 quads from LDS spec: 12 fixed ds_read_b128 per iter.
//    Zero-padded weights make padding/overrun slots free (no predication).
//  - backward: lane owns f = lane+64s (s<9); taps (k1,w1,w2) in registers,
//    reads sdiff[k1],sdiff[k1+1] (read2, broadcast-friendly), spec/buf in
//    registers, spec mirrored to LDS for the next forward.
//  - single wave per block: same-wave LDS ops are in-order -> NO
//    __syncthreads at all. Loss partials go to LDS, reduced once at the end
//    (no per-iter global stores -> no vmcnt drains).
//  - R1/R2 lesson: serial setup kernel cost ~50-100us; now ballot-parallel.
// Stop semantics: speculate 30 iters + loss log -> scan computes S -> repair
// rerun only if S<30 (expected: immediate exit).

#define NSTFT 513
#define NBARK 128
#define BATCH 4
#define TIME  512
#define MAXIT 30
#define NROWS (BATCH*TIME)      // 2048 rows, 1 wave each
#define NQ    12                // quad slots per lane (max pair ~11)

// d_ws layout (bytes). All fields written before read each call.
#define WS_S_OFF   0                          // int: stop iteration S
#define WS_FT_OFF  256                        // float4[NSTFT] taps {k1,w1,k2,w2}
#define WS_QW_OFF  (256 + 16*NSTFT)           // float[NBARK*48] quad weights
#define WS_QM_OFF  (WS_QW_OFF + 4*NBARK*48)   // int2[NBARK] {qbase, nq}
#define WS_BP_OFF  (WS_QM_OFF + 8*NBARK)      // float[MAXIT][NROWS] loss partials

// ---- setup 1: per-freq taps via ballot (block per freq) ----
__global__ __launch_bounds__(64) void setup_taps(const float* __restrict__ fb,
                                                 char* __restrict__ ws) {
    const int f = blockIdx.x, lane = threadIdx.x;
    float wa = fb[(size_t)f*NBARK + lane];
    float wb = fb[(size_t)f*NBARK + 64 + lane];
    unsigned long long ma = __ballot(wa > 0.f);
    unsigned long long mb = __ballot(wb > 0.f);
    if (lane == 0) {
        int k1 = 0, k2 = 0; float w1 = 0.f, w2 = 0.f;
        int c = __popcll(ma) + __popcll(mb);
        unsigned long long a = ma, b = mb;
        if (c >= 1) {
            if (a) { k1 = __ffsll(a) - 1; a &= a - 1; }
            else   { k1 = 64 + __ffsll(b) - 1; b &= b - 1; }
            w1 = fb[(size_t)f*NBARK + k1];
        }
        if (c >= 2) {
            if (a) k2 = __ffsll(a) - 1;
            else   k2 = 64 + __ffsll(b) - 1;
            w2 = fb[(size_t)f*NBARK + k2];
        } else k2 = k1;
        float4 e;
        e.x = __int_as_float(k1); e.y = w1;
        e.z = __int_as_float(k2); e.w = w2;
        ((float4*)(ws + WS_FT_OFF))[f] = e;
    }
}

// ---- setup 2: per-column aligned quad tables (block per column) ----
__global__ __launch_bounds__(64) void setup_quads(char* __restrict__ ws) {
    const int k = blockIdx.x, lane = threadIdx.x;
    const float4* ftab = (const float4*)(ws + WS_FT_OFF);
    int fmin = 1 << 30, fmax = -1;
    for (int j = 0; j < 9; ++j) {
        int f = lane + 64*j;
        if (f < NSTFT) {
            float4 e = ftab[f];
            bool m = (__float_as_int(e.x) == k && e.y > 0.f) ||
                     (__float_as_int(e.z) == k && e.w > 0.f);
            if (m) { fmin = min(fmin, f); fmax = max(fmax, f); }
        }
    }
#pragma unroll
    for (int msk = 32; msk; msk >>= 1) {
        fmin = min(fmin, __shfl_xor(fmin, msk));
        fmax = max(fmax, __shfl_xor(fmax, msk));
    }
    int qbase = 0, nq = 0;
    if (fmax >= 0) {
        qbase = fmin & ~3;
        nq = (((fmax | 3) + 1) - qbase) >> 2;
        if (nq > NQ) nq = NQ;                 // safety clamp (never expected)
    }
    if (lane == 0) ((int2*)(ws + WS_QM_OFF))[k] = make_int2(qbase, nq);
    if (lane < 48) {
        int f = qbase + lane;
        float w = 0.f;
        if (lane < 4*nq && f < NSTFT) {
            float4 e = ftab[f];
            if      (__float_as_int(e.x) == k) w = e.y;
            else if (__float_as_int(e.z) == k) w = e.w;
        }
        ((float*)(ws + WS_QW_OFF))[k*48 + lane] = w;
    }
}

__global__ __launch_bounds__(64, 2) void
iter_kernel(const float* __restrict__ barkspec,
            const float* __restrict__ spec_init,
            float* __restrict__ out,
            char* __restrict__ ws, int mode)
{
    __shared__ float sspec[560];             // spec + zero pad for quad overrun
    __shared__ float sdiff[130];             // diff + pad for k1+1
    __shared__ float slp[MAXIT*64];          // per-iter per-lane loss partials

    const int lane = threadIdx.x;            // single wave per block

    int niter = MAXIT;
    if (mode) {
        int S = *(const volatile int*)(ws + WS_S_OFF);
        if (S >= MAXIT) return;              // expected path: no repair
        niter = S;
    }

    const int r     = blockIdx.x;
    const int batch = r >> 9;
    const int t     = r & (TIME - 1);

    // ---- static tables -> registers (one-time, L2-resident) ----
    const int cA = lane, cB = 127 - lane;    // balanced pair (widths monotone)
    const float* bs = barkspec + (size_t)batch*NBARK*TIME + t;
    const float m0 = bs[cA*TIME];
    const float m1 = bs[cB*TIME];

    const int2*   qmeta = (const int2*)(ws + WS_QM_OFF);
    const float4* qw4   = (const float4*)(ws + WS_QW_OFF);   // [k*12 + sub]
    const int2 qmA = qmeta[cA];
    const int2 qmB = qmeta[cB];
    const int nqA = qmA.y;

    float4 qw[NQ]; int qbyte[NQ];
#pragma unroll
    for (int s = 0; s < NQ; ++s) {
        bool inA = (s < nqA);
        int  sub = inA ? s : (s - nqA);
        int  col = inA ? cA : cB;
        int  qb  = inA ? qmA.x : qmB.x;
        int  nq  = inA ? qmA.y : qmB.y;
        if (sub < nq) {
            qw[s]    = qw4[col*NQ + sub];
            qbyte[s] = (qb + 4*sub) * 4;
        } else {
            qw[s] = make_float4(0.f, 0.f, 0.f, 0.f);
            qbyte[s] = 0;                    // reads sspec[0..3] * 0
        }
    }

    const float4* ftab = (const float4*)(ws + WS_FT_OFF);
    const float* spg = spec_init + ((size_t)batch*TIME + t)*NSTFT;
    int kk[9]; float tw1[9], tw2[9], sp[9], buf[9];
#pragma unroll
    for (int s = 0; s < 9; ++s) {
        int f = lane + 64*s;
        if (f < NSTFT) {
            float4 e = ftab[f];
            kk[s] = __float_as_int(e.x); tw1[s] = e.y; tw2[s] = e.w;
            sp[s] = spg[f];
        } else { kk[s] = 0; tw1[s] = 0.f; tw2[s] = 0.f; sp[s] = 0.f; }
        buf[s] = 0.f;
        sspec[lane + 64*s] = sp[s];          // f>=513 slots get 0 (pad zeroing)
    }
    {   // zero remaining pad [576..560): none; [513..560) covered except...
        int p = 513 + lane;                  // lanes 0..46 zero the tail pad
        if (p < 560) sspec[p] = 0.f;
    }

    float* bp = (float*)(ws + WS_BP_OFF);
    const float GC = -2.0f / (float)NROWS;

    // NOTE: single wave -> same-wave LDS ops execute in order; no barriers.
    for (int it = 0; it < niter; ++it) {
        // ---- forward: 12 aligned float4 LDS reads, dual accumulators
        float accA = 0.f, accB = 0.f;
#pragma unroll
        for (int s = 0; s < NQ; ++s) {
            const float4 v = *(const float4*)((const char*)sspec + qbyte[s]);
            float p = fmaf(v.x, qw[s].x,
                      fmaf(v.y, qw[s].y,
                      fmaf(v.z, qw[s].z, v.w * qw[s].w)));
            bool a = (s < nqA);
            accA += a ? p : 0.f;
            accB += a ? 0.f : p;
        }
        float d0 = m0 - accA;
        float d1 = m1 - accB;
        sdiff[cA] = d0;                      // stride-1, conflict-free
        sdiff[cB] = d1;                      // reversed stride-1, conflict-free
        if (!mode) slp[it*64 + lane] = fmaf(d0, d0, d1*d1);

        // ---- backward + SGD update (reads this iter's sdiff; in-order LDS)
#pragma unroll
        for (int s = 0; s < 9; ++s) {
            float da = sdiff[kk[s]];
            float db = sdiff[kk[s] + 1];     // k2 == k1+1 (or w2==0)
            float g  = GC * fmaf(da, tw1[s], db * tw2[s]);
            float b2 = fmaf(0.9f, buf[s], g);
            buf[s] = b2;
            float v = fmaf(-0.1f, b2, sp[s]);
            v = v < 0.f ? 0.f : v;
            sp[s] = v;
            if (s < 8) sspec[lane + 64*s] = v;
            else if (lane == 0) sspec[512] = v;   // keep pad zeros intact
        }
    }

    // ---- loss epilogue: reduce LDS partials once, store per-iter row loss
    if (!mode) {
        for (int it = 0; it < MAXIT; ++it) {
            float v = slp[it*64 + lane];
#pragma unroll
            for (int msk = 32; msk; msk >>= 1) v += __shfl_xor(v, msk);
            if (lane == 0) bp[it*NROWS + r] = v;
        }
    }

    // ---- store out[batch, f, t] (inherent scatter over f)
    float* og = out + ((size_t)batch*NSTFT)*TIME + t;
#pragma unroll
    for (int s = 0; s < 9; ++s) {
        int f = lane + 64*s;
        if (f < NSTFT) og[(size_t)f*TIME] = sp[s];
    }
}

__global__ __launch_bounds__(256) void scan_kernel(char* __restrict__ ws) {
    __shared__ float red[256];
    __shared__ float losses[MAXIT];
    const int tid = threadIdx.x;
    const float* bp = (const float*)(ws + WS_BP_OFF);
    for (int it = 0; it < MAXIT; ++it) {
        float s = 0.f;
#pragma unroll
        for (int j = 0; j < NROWS/256; ++j) s += bp[it*NROWS + tid + 256*j];
        red[tid] = s;
        __syncthreads();
        for (int h = 128; h; h >>= 1) {
            if (tid < h) red[tid] += red[tid + h];
            __syncthreads();
        }
        if (tid == 0) losses[it] = red[0] * (1.0f/(float)NROWS);
        __syncthreads();
    }
    if (tid == 0) {
        float prev = __builtin_inff();
        int S = MAXIT;
        for (int i = 0; i < MAXIT; ++i) {
            float l = losses[i];
            if (l < 1e-5f || fabsf(prev - l) < 1e-8f) { S = i + 1; break; }
            prev = l;
        }
        *(int*)(ws + WS_S_OFF) = S;
    }
}

extern "C" void kernel_launch(void* const* d_in, const int* in_sizes, int n_in,
                              void* d_out, int out_size, void* d_ws, size_t ws_size,
                              hipStream_t stream)
{
    const float* barkspec  = (const float*)d_in[0];
    const float* fb        = (const float*)d_in[1];
    const float* spec_init = (const float*)d_in[2];
    float* out = (float*)d_out;
    char* ws = (char*)d_ws;

    setup_taps <<<NSTFT, 64, 0, stream>>>(fb, ws);
    setup_quads<<<NBARK, 64, 0, stream>>>(ws);
    iter_kernel<<<NROWS, 64, 0, stream>>>(barkspec, spec_init, out, ws, 0);
    scan_kernel<<<1, 256, 0, stream>>>(ws);
    iter_kernel<<<NROWS, 64, 0, stream>>>(barkspec, spec_init, out, ws, 1);
}

// Round 4
// 108.951 us; speedup vs baseline: 4.6622x; 1.3793x over previous
//
#include <hip/hip_runtime.h>

// InverseBarkScale: 30-iter SGD with momentum inverting a bark filterbank.
// fb (513x128): freq f has taps only at columns (k1(f), k1(f)+1); k1 is
// monotone in f, so the "primary" sets P(c) = {f : k1(f)=c} are contiguous
// and partition [0,513). |P(c)| <= ~3 for c<64, <= 17 for c>=64.
//
// R4: ALL-REGISTER iteration (R3 was LDS-pipe bound at ~320 DS-cyc/iter).
// Lane l owns columns cA=l, cB=127-l AND their primary freqs:
//   spec/buf/w1/w2 in registers (SA=6 + SB=20 slots, zero-padded ->
//   unpredicated loops).
// Cross-lane algebra (all shfl by +-1, snake pairing makes neighbors +-1):
//   proj[c]  = sum_{P(c)} spec*w1  +  carry(c-1),  carry(c)=sum_{P(c)} spec*w2
//     diff[cA=l]     needs carry(l-1)   = lane l-1's A-carry  (shfl_up,  lane0 -> 0)
//     diff[cB=127-l] needs carry(126-l) = lane l+1's B-carry  (shfl_down, lane63 -> own A-carry)
//   grad[f in P(c)] = GC*(diff[c]*w1 + diff[c+1]*w2)
//     A-side needs diff[l+1]   = lane l+1's d0 (shfl_down, lane63 -> own d1)
//     B-side needs diff[128-l] = lane l-1's d1 (shfl_up,   lane0: w2==0 anyway)
// Edge rows f=0 / f=512 have all-zero fb rows: assigned to P(0)/P(127) with
// w=0 -> grad 0 -> spec passes through (init>=0 so clamp is identity). ✓
// Loss: inline 6-shfl wave reduce, lane0 stores bp[row][it]; 30-block
// parallel reduce + 1-thread scan gives stop iteration S; repair launch
// re-runs with S iters only if S<30 (expected: immediate exit).

#define NSTFT 513
#define NBARK 128
#define BATCH 4
#define TIME  512
#define MAXIT 30
#define NROWS (BATCH*TIME)      // 2048 rows, 1 wave each
#define SA 6                    // A-side slots (cols 0..63, narrow: max ~3)
#define SB 20                   // B-side slots (cols 64..127, max 16+1)

// d_ws layout (bytes); ~285 KB. Every field written before read each call.
#define WS_S_OFF   0                          // int: stop iteration S
#define WS_L_OFF   16                         // float[MAXIT]: losses
#define WS_FT_OFF  256                        // float4[NSTFT]: {k1,w1,k2,w2}
#define WS_HA_OFF  8464                       // int2[64]: A {fbase,cnt}
#define WS_HB_OFF  8976                       // int2[64]: B {fbase,cnt}
#define WS_WT_OFF  9488                       // float2[SA+SB][64]: {w1,w2}
#define WS_BP_OFF  22800                      // float[NROWS][32]: loss partials

// ---- setup 1: per-freq taps via ballot (block per freq) ----
__global__ __launch_bounds__(64) void setup_taps(const float* __restrict__ fb,
                                                 char* __restrict__ ws) {
    const int f = blockIdx.x, lane = threadIdx.x;
    float wa = fb[(size_t)f*NBARK + lane];
    float wb = fb[(size_t)f*NBARK + 64 + lane];
    unsigned long long ma = __ballot(wa > 0.f);
    unsigned long long mb = __ballot(wb > 0.f);
    if (lane == 0) {
        int k1 = 0; float w1 = 0.f, w2 = 0.f;
        int c = __popcll(ma) + __popcll(mb);
        unsigned long long a = ma, b = mb;
        if (c >= 1) {
            if (a) { k1 = __ffsll(a) - 1; a &= a - 1; }
            else   { k1 = 64 + __ffsll(b) - 1; b &= b - 1; }
            w1 = fb[(size_t)f*NBARK + k1];
        } else {
            k1 = (f < 256) ? 0 : 127;        // all-zero row: attach to edge
        }
        if (c >= 2) {
            int k2 = a ? (__ffsll(a) - 1) : (64 + __ffsll(b) - 1);
            w2 = fb[(size_t)f*NBARK + k2];   // k2 == k1+1 (consecutive taps)
        }
        float4 e;
        e.x = __int_as_float(k1); e.y = w1;
        e.z = 0.f;                e.w = w2;
        ((float4*)(ws + WS_FT_OFF))[f] = e;
    }
}

// ---- setup 2: per-lane packed tables (block per column) ----
__global__ __launch_bounds__(64) void setup_lanes(char* __restrict__ ws) {
    const int c = blockIdx.x, lane = threadIdx.x;
    const float4* ftab = (const float4*)(ws + WS_FT_OFF);
    int fmin = 0x7fffffff, fmax = -1;
    for (int s = 0; s < 9; ++s) {
        int f = lane + 64*s;
        if (f < NSTFT) {
            float4 e = ftab[f];
            if (__float_as_int(e.x) == c) { fmin = min(fmin, f); fmax = max(fmax, f); }
        }
    }
#pragma unroll
    for (int m = 32; m; m >>= 1) {
        fmin = min(fmin, __shfl_xor(fmin, m));
        fmax = max(fmax, __shfl_xor(fmax, m));
    }
    int cnt = (fmax >= 0) ? (fmax - fmin + 1) : 0;
    if (fmax < 0) fmin = 0;
    const int cap  = (c < 64) ? SA : SB;
    const int base = (c < 64) ? 0  : SA;
    const int lf   = (c < 64) ? c  : 127 - c;
    cnt = min(cnt, cap);
    if (lane == 0)
        ((int2*)(ws + (c < 64 ? WS_HA_OFF : WS_HB_OFF)))[lf] = make_int2(fmin, cnt);
    if (lane < cap) {
        float2 wv = make_float2(0.f, 0.f);
        int f = fmin + lane;
        if (lane < cnt && f < NSTFT) {
            float4 e = ftab[f];
            if (__float_as_int(e.x) == c) wv = make_float2(e.y, e.w);
        }
        ((float2*)(ws + WS_WT_OFF))[(base + lane)*64 + lf] = wv;
    }
}

__global__ __launch_bounds__(64, 2) void
iter_kernel(const float* __restrict__ barkspec,
            const float* __restrict__ spec_init,
            float* __restrict__ out,
            char* __restrict__ ws, int mode)
{
    const int lane = threadIdx.x;            // single wave per block, no LDS

    int niter = MAXIT;
    if (mode) {
        int S = *(const volatile int*)(ws + WS_S_OFF);
        if (S >= MAXIT) return;              // expected path: no repair
        niter = S;
    }

    const int r     = blockIdx.x;
    const int batch = r >> 9;
    const int t     = r & (TIME - 1);

    // ---- per-lane tables -> registers ----
    const int2 hA = ((const int2*)(ws + WS_HA_OFF))[lane];
    const int2 hB = ((const int2*)(ws + WS_HB_OFF))[lane];
    const float2* wt = (const float2*)(ws + WS_WT_OFF);
    const float* spg = spec_init + ((size_t)batch*TIME + t)*NSTFT;

    float w1A[SA], w2A[SA], spA[SA], bfA[SA];
    float w1B[SB], w2B[SB], spB[SB], bfB[SB];
#pragma unroll
    for (int i = 0; i < SA; ++i) {
        float2 v = wt[i*64 + lane];
        w1A[i] = v.x; w2A[i] = v.y;
        spA[i] = (i < hA.y) ? spg[hA.x + i] : 0.f;
        bfA[i] = 0.f;
    }
#pragma unroll
    for (int i = 0; i < SB; ++i) {
        float2 v = wt[(SA + i)*64 + lane];
        w1B[i] = v.x; w2B[i] = v.y;
        spB[i] = (i < hB.y) ? spg[hB.x + i] : 0.f;
        bfB[i] = 0.f;
    }

    const float* bs = barkspec + (size_t)batch*NBARK*TIME + t;
    const float m0 = bs[(size_t)lane*TIME];          // col cA = lane
    const float m1 = bs[(size_t)(127 - lane)*TIME];  // col cB = 127-lane

    float* bp = (float*)(ws + WS_BP_OFF) + (size_t)r*32;
    const float GC = -2.0f / (float)NROWS;

    for (int it = 0; it < niter; ++it) {
        // ---- forward: per-column partial sums (unpredicated; pads are 0)
        float sAA = 0.f, sBA = 0.f, sAB = 0.f, sBB = 0.f;
#pragma unroll
        for (int i = 0; i < SA; ++i) {
            sAA = fmaf(spA[i], w1A[i], sAA);
            sBA = fmaf(spA[i], w2A[i], sBA);
        }
#pragma unroll
        for (int i = 0; i < SB; ++i) {
            sAB = fmaf(spB[i], w1B[i], sAB);
            sBB = fmaf(spB[i], w2B[i], sBB);
        }
        float cAin = __shfl_up(sBA, 1);  if (lane == 0)  cAin = 0.f;
        float cBin = __shfl_down(sBB, 1); if (lane == 63) cBin = sBA;
        const float d0 = m0 - (sAA + cAin);
        const float d1 = m1 - (sAB + cBin);

        if (!mode) {
            float lp = fmaf(d0, d0, d1*d1);
#pragma unroll
            for (int m = 32; m; m >>= 1) lp += __shfl_xor(lp, m);
            if (lane == 0) bp[it] = lp;  // fire-and-forget, 30 consecutive
        }

        // ---- backward + SGD update
        float dAn = __shfl_down(d0, 1); if (lane == 63) dAn = d1;
        float dBn = __shfl_up(d1, 1);   // lane0: its w2B are all 0
#pragma unroll
        for (int i = 0; i < SA; ++i) {
            float g = GC * fmaf(d0, w1A[i], dAn * w2A[i]);
            bfA[i] = fmaf(0.9f, bfA[i], g);
            float v = fmaf(-0.1f, bfA[i], spA[i]);
            spA[i] = v < 0.f ? 0.f : v;
        }
#pragma unroll
        for (int i = 0; i < SB; ++i) {
            float g = GC * fmaf(d1, w1B[i], dBn * w2B[i]);
            bfB[i] = fmaf(0.9f, bfB[i], g);
            float v = fmaf(-0.1f, bfB[i], spB[i]);
            spB[i] = v < 0.f ? 0.f : v;
        }
    }

    // ---- store out[batch, f, t] (scatter over f; each f stored once)
    float* og = out + ((size_t)batch*NSTFT)*TIME + t;
#pragma unroll
    for (int i = 0; i < SA; ++i)
        if (i < hA.y) og[(size_t)(hA.x + i)*TIME] = spA[i];
#pragma unroll
    for (int i = 0; i < SB; ++i)
        if (i < hB.y) og[(size_t)(hB.x + i)*TIME] = spB[i];
}

// ---- loss reduce: block per iteration ----
__global__ __launch_bounds__(256) void scan_reduce(char* __restrict__ ws) {
    __shared__ float wsum[4];
    const int it = blockIdx.x, tid = threadIdx.x;
    const int wave = tid >> 6, lane = tid & 63;
    const float* bp = (const float*)(ws + WS_BP_OFF);
    float s = 0.f;
#pragma unroll
    for (int j = 0; j < NROWS/256; ++j)
        s += bp[(size_t)(tid + 256*j)*32 + it];
#pragma unroll
    for (int m = 32; m; m >>= 1) s += __shfl_xor(s, m);
    if (lane == 0) wsum[wave] = s;
    __syncthreads();
    if (tid == 0)
        ((float*)(ws + WS_L_OFF))[it] =
            (wsum[0] + wsum[1] + wsum[2] + wsum[3]) * (1.0f/(float)NROWS);
}

__global__ void scan_final(char* __restrict__ ws) {
    // reference stop logic: update applied on the stop iteration, frozen
    // after -> S = first stop index + 1, else MAXIT
    const float* losses = (const float*)(ws + WS_L_OFF);
    float prev = __builtin_inff();
    int S = MAXIT;
    for (int i = 0; i < MAXIT; ++i) {
        float l = losses[i];
        if (l < 1e-5f || fabsf(prev - l) < 1e-8f) { S = i + 1; break; }
        prev = l;
    }
    *(int*)(ws + WS_S_OFF) = S;
}

extern "C" void kernel_launch(void* const* d_in, const int* in_sizes, int n_in,
                              void* d_out, int out_size, void* d_ws, size_t ws_size,
                              hipStream_t stream)
{
    const float* barkspec  = (const float*)d_in[0];
    const float* fb        = (const float*)d_in[1];
    const float* spec_init = (const float*)d_in[2];
    float* out = (float*)d_out;
    char* ws = (char*)d_ws;

    setup_taps <<<NSTFT, 64, 0, stream>>>(fb, ws);
    setup_lanes<<<NBARK, 64, 0, stream>>>(ws);
    iter_kernel<<<NROWS, 64, 0, stream>>>(barkspec, spec_init, out, ws, 0);
    scan_reduce<<<MAXIT, 256, 0, stream>>>(ws);
    scan_final <<<1, 1, 0, stream>>>(ws);
    iter_kernel<<<NROWS, 64, 0, stream>>>(barkspec, spec_init, out, ws, 1);
}